// Round 2
// baseline (158.761 us; speedup 1.0000x reference)
//
#include <hip/hip_runtime.h>

typedef float f4 __attribute__((ext_vector_type(4)));

#define N_SEL   8192
#define N_FEAT  256
#define K_SUB   256
#define N_PERS  4
#define E_FULL  262144
#define E_RAW   262144
#define N_TOTAL 8192
#define EPSILON 0.5f
#define LAMB1   0.5f

// Workspace layout (total ~8.4 MB):
//  [0, 128K)        : invn[N_SEL][4] f32
//  [128K, 129K)     : score[K_SUB]   f32
//  [132K, 132K+4M)  : xb[N_SEL][256] bf16 (ushort)
//  [+4M, +8M)       : pass list, E_FULL x int4 {i, j, val_bits, pad}
//  [+8M, +8M+4)     : pass counter
#define WS_SCORE_OFF  (128 * 1024)
#define WS_XB_OFF     (132 * 1024)
#define WS_LIST_OFF   (WS_XB_OFF + 4 * 1024 * 1024)
#define WS_CNT_OFF    (WS_LIST_OFF + E_FULL * 16)

static __device__ __forceinline__ unsigned short f2b(float f) {
    unsigned u = __float_as_uint(f);
    unsigned r = u + 0x7FFFu + ((u >> 16) & 1u);   // RNE to bf16
    return (unsigned short)(r >> 16);
}
static __device__ __forceinline__ float b2f(unsigned short s) {
    return __uint_as_float((unsigned)s << 16);
}

// ---------------- 256 MB output zero: full-line nontemporal dwordx4 ----------------
__global__ __launch_bounds__(256) void zero_kernel(f4* __restrict__ p, int n4) {
    int idx = blockIdx.x * 256 + threadIdx.x;
    int stride = gridDim.x * 256;
    f4 z = (f4)0.0f;
    for (int i = idx; i < n4; i += stride)
        __builtin_nontemporal_store(z, p + i);
}

// ---------------- prep: inverse norms + bf16 convert + counter zero ----------------
// one wave per (n,p); lane handles 4 dims
__global__ __launch_bounds__(256) void prep_kernel(const f4* __restrict__ x4,
                                                   const f4* __restrict__ w4,
                                                   float* __restrict__ invn,
                                                   ushort4* __restrict__ xb,
                                                   int* __restrict__ cnt) {
    if (blockIdx.x == 0 && threadIdx.x == 0) *cnt = 0;
    int wave = (blockIdx.x * 256 + threadIdx.x) >> 6;
    int lane = threadIdx.x & 63;
    int n = wave >> 2;
    int p = wave & 3;
    f4 xv = x4[(size_t)n * 64 + lane];
    f4 wv = w4[p * 64 + lane];
    if (p == 0) {
        ushort4 b;
        b.x = f2b(xv.x); b.y = f2b(xv.y); b.z = f2b(xv.z); b.w = f2b(xv.w);
        xb[(size_t)n * 64 + lane] = b;
    }
    float a = xv.x * wv.x, b_ = xv.y * wv.y, c = xv.z * wv.z, d = xv.w * wv.w;
    float s = a * a + b_ * b_ + c * c + d * d;
    #pragma unroll
    for (int off = 32; off; off >>= 1) s += __shfl_xor(s, off);
    if (lane == 0) invn[n * 4 + p] = 1.0f / (sqrtf(s) + 1e-12f);
}

// ---------------- deterministic score normalization (one block) ----------------
__global__ __launch_bounds__(256) void score_kernel(const float* __restrict__ s,
                                                    const int* __restrict__ belong,
                                                    float* __restrict__ score) {
    __shared__ float sv[K_SUB];
    __shared__ int bv[K_SUB];
    int t = threadIdx.x;
    sv[t] = s[t];
    bv[t] = belong[t];
    __syncthreads();
    int myb = bv[t];
    float sum = 0.0f;
    for (int k = 0; k < K_SUB; ++k)
        if (bv[k] == myb) sum += sv[k];
    score[t] = sv[t] / sum;
}

// ---------------- masked-edge weighted cosine; passing edges -> list ----------------
__global__ __launch_bounds__(256) void edge_kernel(const ushort4* __restrict__ xb,
                                                   const f4* __restrict__ w4,
                                                   const int* __restrict__ fe,
                                                   const int* __restrict__ sel_batch,
                                                   const f4* __restrict__ invn4,
                                                   const float* __restrict__ score,
                                                   int4* __restrict__ list,
                                                   int* __restrict__ cnt) {
    int lane   = threadIdx.x & 63;
    int waveId = (blockIdx.x * blockDim.x + threadIdx.x) >> 6;
    int nWaves = (gridDim.x * blockDim.x) >> 6;

    // per-lane squared weights, 4 perspectives x 4 dims (registers)
    f4 q0 = w4[0 * 64 + lane];
    f4 q1 = w4[1 * 64 + lane];
    f4 q2 = w4[2 * 64 + lane];
    f4 q3 = w4[3 * 64 + lane];
    q0 *= q0; q1 *= q1; q2 *= q2; q3 *= q3;

    for (int e = waveId; e < E_FULL; e += nWaves) {
        int i = fe[e];
        int j = fe[E_FULL + e];
        if (i == j) continue;  // self-loop removal (wave-uniform)

        ushort4 si = xb[(size_t)i * 64 + lane];
        ushort4 sj = xb[(size_t)j * 64 + lane];
        float px = b2f(si.x) * b2f(sj.x);
        float py = b2f(si.y) * b2f(sj.y);
        float pz = b2f(si.z) * b2f(sj.z);
        float pw = b2f(si.w) * b2f(sj.w);
        float a0 = px * q0.x + py * q0.y + pz * q0.z + pw * q0.w;
        float a1 = px * q1.x + py * q1.y + pz * q1.z + pw * q1.w;
        float a2 = px * q2.x + py * q2.y + pz * q2.z + pw * q2.w;
        float a3 = px * q3.x + py * q3.y + pz * q3.z + pw * q3.w;

        // fold inverse norms before the cross-lane reduce (one butterfly, not four)
        f4 ii = invn4[i];
        f4 ij = invn4[j];
        float v = a0 * (ii.x * ij.x) + a1 * (ii.y * ij.y) +
                  a2 * (ii.z * ij.z) + a3 * (ii.w * ij.w);
        #pragma unroll
        for (int off = 32; off; off >>= 1) v += __shfl_xor(v, off);

        if (lane == 0) {
            v *= 0.25f;  // mean over perspectives
            if (v > EPSILON) {
                float val = v * score[sel_batch[i]] * LAMB1;
                int idx = atomicAdd(cnt, 1);
                int4 ent; ent.x = i; ent.y = j; ent.z = __float_as_int(val); ent.w = 0;
                list[idx] = ent;
            }
        }
    }
}

// ---------------- dedup passing edges (mask .set semantics) + scatter ----------------
__global__ __launch_bounds__(256) void finalize_kernel(const int4* __restrict__ list,
                                                       const int* __restrict__ cnt,
                                                       const int* __restrict__ sel_map,
                                                       float* __restrict__ out) {
    int k = blockIdx.x * 256 + threadIdx.x;
    int n = *cnt;
    if (k >= n) return;
    int4 ek = list[k];
    for (int l = 0; l < k; ++l) {          // first-occurrence wins; dups identical
        int4 el = list[l];
        if (el.x == ek.x && el.y == ek.y) return;
    }
    atomicAdd(&out[(size_t)sel_map[ek.x] * N_TOTAL + sel_map[ek.y]],
              __int_as_float(ek.z));
}

// ---------------- raw graph scatter (duplicates accumulate) ----------------
__global__ __launch_bounds__(256) void raw_kernel(const int* __restrict__ re,
                                                  float* __restrict__ out) {
    int t = blockIdx.x * 256 + threadIdx.x;
    if (t < E_RAW) {
        int u = re[t];
        int v = re[E_RAW + t];
        atomicAdd(&out[(size_t)u * N_TOTAL + v], 1.0f - LAMB1);
    }
}

extern "C" void kernel_launch(void* const* d_in, const int* in_sizes, int n_in,
                              void* d_out, int out_size, void* d_ws, size_t ws_size,
                              hipStream_t stream) {
    const float* x         = (const float*)d_in[0];
    const float* mw        = (const float*)d_in[1];
    const int* sel_batch   = (const int*)d_in[2];
    const int* sel_map     = (const int*)d_in[3];
    const float* sel_score = (const float*)d_in[5];
    const int* sel_belong  = (const int*)d_in[4];
    const int* fe          = (const int*)d_in[6];
    const int* re          = (const int*)d_in[7];
    float* out             = (float*)d_out;

    char* ws       = (char*)d_ws;
    float* invn    = (float*)ws;
    float* score   = (float*)(ws + WS_SCORE_OFF);
    ushort4* xb    = (ushort4*)(ws + WS_XB_OFF);
    int4* list     = (int4*)(ws + WS_LIST_OFF);
    int* cnt       = (int*)(ws + WS_CNT_OFF);

    // 256 MB output zero, full-line nontemporal stores (no fillBuffer 4x amplification)
    zero_kernel<<<4096, 256, 0, stream>>>((f4*)out, (N_TOTAL * N_TOTAL) / 4);

    prep_kernel<<<(N_SEL * N_PERS * 64) / 256, 256, 0, stream>>>(
        (const f4*)x, (const f4*)mw, invn, xb, cnt);
    score_kernel<<<1, 256, 0, stream>>>(sel_score, sel_belong, score);
    edge_kernel<<<2048, 256, 0, stream>>>(
        xb, (const f4*)mw, fe, sel_batch, (const f4*)invn, score, list, cnt);
    finalize_kernel<<<E_FULL / 256, 256, 0, stream>>>(list, cnt, sel_map, out);
    raw_kernel<<<(E_RAW + 255) / 256, 256, 0, stream>>>(re, out);
}

// Round 3
// 115.064 us; speedup vs baseline: 1.3798x; 1.3798x over previous
//
#include <hip/hip_runtime.h>

typedef float f4 __attribute__((ext_vector_type(4)));
typedef unsigned short us8 __attribute__((ext_vector_type(8)));

#define N_SEL   8192
#define N_FEAT  256
#define K_SUB   256
#define N_PERS  4
#define E_FULL  262144
#define E_RAW   262144
#define N_TOTAL 8192
#define EPSILON 0.5f
#define LAMB1   0.5f

// Workspace layout:
//  [0, 128K)        : invn[N_SEL][4] f32
//  [128K, 129K)     : score[K_SUB]   f32
//  [132K, 132K+4M)  : xb[N_SEL][256] bf16
//  [+4M, +8M)       : pass list, int4 {i, j, val_bits, 0}
//  [+8M]            : pass counter
#define WS_SCORE_OFF  (128 * 1024)
#define WS_XB_OFF     (132 * 1024)
#define WS_LIST_OFF   (WS_XB_OFF + 4 * 1024 * 1024)
#define WS_CNT_OFF    (WS_LIST_OFF + E_FULL * 16)

// out zero split: 4096 zero-blocks x 13 f4-iters, 4096 edge-blocks x 3 f4-iters
#define ZB_ITERS 13
#define EB_ITERS 3
#define ZB_TOTAL_F4 (4096 * ZB_ITERS * 256)   // 13,631,488

#define B2F(s) __uint_as_float(((unsigned)(s)) << 16)

static __device__ __forceinline__ unsigned short f2b(float f) {
    unsigned u = __float_as_uint(f);
    unsigned r = u + 0x7FFFu + ((u >> 16) & 1u);   // RNE
    return (unsigned short)(r >> 16);
}

// ---------------- K1: inverse norms + bf16 convert + score + cnt=0 ----------------
__global__ __launch_bounds__(256) void prep_kernel(const f4* __restrict__ x4,
                                                   const f4* __restrict__ w4,
                                                   float* __restrict__ invn,
                                                   ushort4* __restrict__ xb,
                                                   int* __restrict__ cnt,
                                                   const float* __restrict__ s,
                                                   const int* __restrict__ belong,
                                                   float* __restrict__ score) {
    __shared__ float sv[K_SUB];
    __shared__ int bv[K_SUB];
    int wave = (blockIdx.x * 256 + threadIdx.x) >> 6;
    int lane = threadIdx.x & 63;
    int n = wave >> 2;
    int p = wave & 3;
    f4 xv = x4[(size_t)n * 64 + lane];
    f4 wv = w4[p * 64 + lane];
    if (p == 0) {
        ushort4 b;
        b.x = f2b(xv.x); b.y = f2b(xv.y); b.z = f2b(xv.z); b.w = f2b(xv.w);
        xb[(size_t)n * 64 + lane] = b;
    }
    f4 h = xv * wv;
    float ss = h.x * h.x + h.y * h.y + h.z * h.z + h.w * h.w;
    #pragma unroll
    for (int off = 32; off; off >>= 1) ss += __shfl_xor(ss, off);
    if (lane == 0) invn[n * 4 + p] = 1.0f / (sqrtf(ss) + 1e-12f);

    if (blockIdx.x == 0) {
        int t = threadIdx.x;
        if (t == 0) *cnt = 0;
        sv[t] = s[t];
        bv[t] = belong[t];
        __syncthreads();
        int myb = bv[t];
        float sum = 0.0f;
        for (int k = 0; k < K_SUB; ++k)
            if (bv[k] == myb) sum += sv[k];
        score[t] = sv[t] / sum;
    }
}

// ---------------- K2: zero(out) [XCDs 0-3] || edge cosine [XCDs 4-7] ----------------
// blockIdx%8<4 -> zero role; else edge role (4 edges/wave, 16 lanes/edge).
// Edge blocks zero a tail region after their edges (load balance).
__global__ __launch_bounds__(256) void zero_edge_kernel(f4* __restrict__ out4,
                                                        const us8* __restrict__ xb8,
                                                        const f4* __restrict__ w4,
                                                        const int* __restrict__ fe,
                                                        const int* __restrict__ sel_batch,
                                                        const f4* __restrict__ invn4,
                                                        const float* __restrict__ score,
                                                        int4* __restrict__ list,
                                                        int* __restrict__ cnt) {
    int b = blockIdx.x;
    int r = b & 7;
    int t = threadIdx.x;
    f4 z = (f4)0.0f;

    if (r < 4) {                        // ---- zero role ----
        int zi = (b >> 3) * 4 + r;      // [0, 4096)
        f4* p = out4 + (size_t)zi * (ZB_ITERS * 256);
        #pragma unroll
        for (int it = 0; it < ZB_ITERS; ++it)
            p[it * 256 + t] = z;
        return;
    }

    // ---- edge role ----
    int ei   = (b >> 3) * 4 + (r - 4);  // [0, 4096)
    int lane = t & 63;
    int l16  = lane & 15;
    int sub  = lane >> 4;
    int ew   = ei * 4 + (t >> 6);       // edge-wave id [0, 16384)

    // per-lane squared weights: dims [l16*16, l16*16+16), 4 perspectives
    float q0[16], q1[16], q2[16], q3[16];
    #pragma unroll
    for (int g = 0; g < 4; ++g) {
        f4 w0 = w4[0 * 64 + l16 * 4 + g];
        f4 w1 = w4[1 * 64 + l16 * 4 + g];
        f4 w2 = w4[2 * 64 + l16 * 4 + g];
        f4 w3 = w4[3 * 64 + l16 * 4 + g];
        q0[g*4+0] = w0.x*w0.x; q0[g*4+1] = w0.y*w0.y; q0[g*4+2] = w0.z*w0.z; q0[g*4+3] = w0.w*w0.w;
        q1[g*4+0] = w1.x*w1.x; q1[g*4+1] = w1.y*w1.y; q1[g*4+2] = w1.z*w1.z; q1[g*4+3] = w1.w*w1.w;
        q2[g*4+0] = w2.x*w2.x; q2[g*4+1] = w2.y*w2.y; q2[g*4+2] = w2.z*w2.z; q2[g*4+3] = w2.w*w2.w;
        q3[g*4+0] = w3.x*w3.x; q3[g*4+1] = w3.y*w3.y; q3[g*4+2] = w3.z*w3.z; q3[g*4+3] = w3.w*w3.w;
    }

    for (int e4 = ew * 4; e4 < E_FULL; e4 += 16384 * 4) {
        int e = e4 + sub;
        int i = fe[e];
        int j = fe[E_FULL + e];
        const us8* ri = xb8 + (size_t)i * 32;
        const us8* rj = xb8 + (size_t)j * 32;
        us8 xi0 = ri[2 * l16], xi1 = ri[2 * l16 + 1];
        us8 xj0 = rj[2 * l16], xj1 = rj[2 * l16 + 1];

        float a0 = 0.f, a1 = 0.f, a2 = 0.f, a3 = 0.f;
        #pragma unroll
        for (int k = 0; k < 8; ++k) {
            float p0 = B2F(xi0[k]) * B2F(xj0[k]);   // dim k
            float p1 = B2F(xi1[k]) * B2F(xj1[k]);   // dim k+8
            a0 = fmaf(p1, q0[k + 8], fmaf(p0, q0[k], a0));
            a1 = fmaf(p1, q1[k + 8], fmaf(p0, q1[k], a1));
            a2 = fmaf(p1, q2[k + 8], fmaf(p0, q2[k], a2));
            a3 = fmaf(p1, q3[k + 8], fmaf(p0, q3[k], a3));
        }
        f4 ii = invn4[i];
        f4 ij = invn4[j];
        float v = a0 * (ii.x * ij.x) + a1 * (ii.y * ij.y) +
                  a2 * (ii.z * ij.z) + a3 * (ii.w * ij.w);
        v += __shfl_xor(v, 1);
        v += __shfl_xor(v, 2);
        v += __shfl_xor(v, 4);
        v += __shfl_xor(v, 8);

        if (l16 == 0 && i != j) {
            v *= 0.25f;
            if (v > EPSILON) {
                float val = v * score[sel_batch[i]] * LAMB1;
                int idx = atomicAdd(cnt, 1);
                int4 ent; ent.x = i; ent.y = j; ent.z = __float_as_int(val); ent.w = 0;
                list[idx] = ent;
            }
        }
    }

    // tail zeroing (after edges; other blocks never read out in this kernel)
    f4* p = out4 + ZB_TOTAL_F4 + (size_t)ei * (EB_ITERS * 256);
    #pragma unroll
    for (int it = 0; it < EB_ITERS; ++it)
        p[it * 256 + t] = z;
}

// ---------------- K3: raw scatter + dedup'd pass-list scatter ----------------
__global__ __launch_bounds__(256) void raw_finalize_kernel(const int* __restrict__ re,
                                                           const int4* __restrict__ list,
                                                           const int* __restrict__ cnt,
                                                           const int* __restrict__ sel_map,
                                                           float* __restrict__ out) {
    int t = blockIdx.x * 256 + threadIdx.x;
    if (t < E_RAW) {
        int u = re[t];
        int v = re[E_RAW + t];
        atomicAdd(&out[(size_t)u * N_TOTAL + v], 1.0f - LAMB1);
    }
    int n = *cnt;
    if (t < n) {
        int4 ek = list[t];
        bool first = true;
        for (int l = 0; l < t; ++l) {       // first occurrence wins; dups identical
            int4 el = list[l];
            if (el.x == ek.x && el.y == ek.y) { first = false; break; }
        }
        if (first)
            atomicAdd(&out[(size_t)sel_map[ek.x] * N_TOTAL + sel_map[ek.y]],
                      __int_as_float(ek.z));
    }
}

extern "C" void kernel_launch(void* const* d_in, const int* in_sizes, int n_in,
                              void* d_out, int out_size, void* d_ws, size_t ws_size,
                              hipStream_t stream) {
    const float* x         = (const float*)d_in[0];
    const float* mw        = (const float*)d_in[1];
    const int* sel_batch   = (const int*)d_in[2];
    const int* sel_map     = (const int*)d_in[3];
    const int* sel_belong  = (const int*)d_in[4];
    const float* sel_score = (const float*)d_in[5];
    const int* fe          = (const int*)d_in[6];
    const int* re          = (const int*)d_in[7];
    float* out             = (float*)d_out;

    char* ws       = (char*)d_ws;
    float* invn    = (float*)ws;
    float* score   = (float*)(ws + WS_SCORE_OFF);
    ushort4* xb    = (ushort4*)(ws + WS_XB_OFF);
    int4* list     = (int4*)(ws + WS_LIST_OFF);
    int* cnt       = (int*)(ws + WS_CNT_OFF);

    prep_kernel<<<8192, 256, 0, stream>>>(
        (const f4*)x, (const f4*)mw, invn, xb, cnt, sel_score, sel_belong, score);
    zero_edge_kernel<<<8192, 256, 0, stream>>>(
        (f4*)out, (const us8*)xb, (const f4*)mw, fe, sel_batch,
        (const f4*)invn, score, list, cnt);
    raw_finalize_kernel<<<1024, 256, 0, stream>>>(re, list, cnt, sel_map, out);
}